// Round 3
// baseline (141.703 us; speedup 1.0000x reference)
//
#include <hip/hip_runtime.h>
#include <hip/hip_bf16.h>
#include <cstdint>

#define IDIM 1024
#define HID  256

typedef __attribute__((ext_vector_type(4))) float f32x4;
typedef __attribute__((ext_vector_type(8))) short short8;
typedef __attribute__((ext_vector_type(4))) unsigned int u32x4;

__device__ __forceinline__ unsigned pk_bf16(float a, float b) {
  __hip_bfloat162 h = __float22bfloat162_rn(make_float2(a, b));
  unsigned r; __builtin_memcpy(&r, &h, 4); return r;
}

__device__ __forceinline__ void gl2lds16(const void* src, void* dst) {
  __builtin_amdgcn_global_load_lds(
      reinterpret_cast<const __attribute__((address_space(1))) unsigned int*>(
          reinterpret_cast<uintptr_t>(src)),
      reinterpret_cast<__attribute__((address_space(3))) unsigned int*>(
          reinterpret_cast<uintptr_t>(dst)),
      16, 0, 0);
}

// ---------------------------------------------------------------------------
// Prep: W1bT[n][k] = bf16(ln_w[k] * W1[k][n]); t2[n]=sum ln_w*W1; tc1=sum ln_b*W1+b1
// 64 blocks x 256 thr; thread (ni=t&3, kg=t>>2) owns col b*4+ni, k [kg*16,+16).
// ---------------------------------------------------------------------------
__global__ __launch_bounds__(256)
void prep_kernel(const float* __restrict__ W1, const float* __restrict__ lnw,
                 const float* __restrict__ lnb, const float* __restrict__ b1,
                 unsigned short* __restrict__ w1bt, float* __restrict__ t2g,
                 float* __restrict__ tc1g) {
  const int t  = threadIdx.x;
  const int ni = t & 3, kg = t >> 2;
  const int n  = blockIdx.x * 4 + ni;
  const int k0 = kg * 16;
  float s1 = 0.f, s2 = 0.f;
  unsigned pk[8];
#pragma unroll
  for (int j = 0; j < 16; j += 2) {
    const int k = k0 + j;
    const float v0 = W1[(size_t)k * HID + n];
    const float v1 = W1[(size_t)(k + 1) * HID + n];
    const float sc0 = lnw[k] * v0, sc1 = lnw[k + 1] * v1;
    s2 += sc0 + sc1;
    s1 = fmaf(lnb[k], v0, fmaf(lnb[k + 1], v1, s1));
    pk[j >> 1] = pk_bf16(sc0, sc1);
  }
  u32x4* dst = reinterpret_cast<u32x4*>(w1bt + (size_t)n * IDIM + k0);
  dst[0] = u32x4{pk[0], pk[1], pk[2], pk[3]};
  dst[1] = u32x4{pk[4], pk[5], pk[6], pk[7]};
  __shared__ float red[2][64][4];
  red[0][kg][ni] = s1; red[1][kg][ni] = s2;
  __syncthreads();
  if (t < 4) {
    float a = 0.f, b = 0.f;
    for (int i = 0; i < 64; ++i) { a += red[0][i][t]; b += red[1][i][t]; }
    const int nn = blockIdx.x * 4 + t;
    tc1g[nn] = a + b1[nn];
    t2g[nn]  = b;
  }
}

// ---------------------------------------------------------------------------
// Head. Block = 64 rows x 256 cols, 4 waves, BK=32, 32 K-steps.
// ALL loop VMEM = global_load_lds (A fp32 8KiB + B bf16 16KiB per step, dbuf).
// Counted s_waitcnt vmcnt(6) per step — next step's 6 loads stay in flight
// across barriers (T4). Swizzles (G21, involutions):
//   A [64 rows][8 chunks x16B]: phys p holds logical p^(row&7)
//   B [128 lines][8 chunks x16B]: line=row>>1; c=kc+4*(row&1); p=c^(L&7)
// Stats computed from fp32 fragment reads (each wave tiles the step once).
// ---------------------------------------------------------------------------
__global__ __launch_bounds__(256, 3)
void head_kernel(const float* __restrict__ emb,
                 const unsigned short* __restrict__ w1bt,
                 const float* __restrict__ t2g, const float* __restrict__ tc1g,
                 const float* __restrict__ w2g, const float* __restrict__ b2g,
                 float* __restrict__ out) {
  __shared__ __align__(16) char smem[53248];
  // [0,16384): A fp32 dbuf [2][8192] ; [16384,49152): B dbuf [2][16384]
  float* const stats = reinterpret_cast<float*>(smem + 49152);  // 4w x 64r x 2
  float* const pout  = reinterpret_cast<float*>(smem + 51200);  // 256 x 2

  const int t  = threadIdx.x;
  const int l  = t & 63;
  const int w  = t >> 6;
  const int lr = l & 15;
  const int lk = l >> 4;
  const int m0 = blockIdx.x * 64;

  // staging lane constants (pre-swizzled global sources)
  const int lhi = l >> 3;          // 0..7 == (dest row|line) & 7
  const int lc  = (l & 7) ^ lhi;   // logical chunk feeding phys slot l&7
  const float* const aSrc0 = emb + (size_t)(m0 + w * 16 + lhi) * IDIM + lc * 4;
  const float* const aSrc1 = emb + (size_t)(m0 + w * 16 + 8 + lhi) * IDIM + lc * 4;
  const unsigned short* bSrc[4];
#pragma unroll
  for (int i = 0; i < 4; ++i) {
    const int row = (w * 4 + i) * 16 + 2 * lhi + (lc >> 2);
    bSrc[i] = w1bt + (size_t)row * IDIM + (lc & 3) * 8;
  }

  // fragment-read byte offsets (within a buffer)
  const int aOff0 = lr * 128 + ((2 * lk) ^ (lr & 7)) * 16;
  const int aOff1 = lr * 128 + ((2 * lk + 1) ^ (lr & 7)) * 16;
  const int bOff  = (w * 32 + (lr >> 1)) * 128 +
                    ((lk + ((lr & 1) << 2)) ^ (lr >> 1)) * 16;

  f32x4 acc[4][4];
#pragma unroll
  for (int i = 0; i < 4; ++i)
#pragma unroll
    for (int j = 0; j < 4; ++j) acc[i][j] = f32x4{0.f, 0.f, 0.f, 0.f};
  float sum4[4] = {0.f, 0.f, 0.f, 0.f}, ssq4[4] = {0.f, 0.f, 0.f, 0.f};

  auto stage = [&](int s, int buf) {
    char* const Ad = smem + buf * 8192 + w * 2048;
    char* const Bd = smem + 16384 + buf * 16384 + w * 4096;
    gl2lds16(aSrc0 + s * 32, Ad);
    gl2lds16(aSrc1 + s * 32, Ad + 1024);
    gl2lds16(bSrc[0] + s * 32, Bd);
    gl2lds16(bSrc[1] + s * 32, Bd + 1024);
    gl2lds16(bSrc[2] + s * 32, Bd + 2048);
    gl2lds16(bSrc[3] + s * 32, Bd + 3072);
  };
  auto compute = [&](int buf) {
    const char* const Af = smem + buf * 8192;
    const char* const Bf = smem + 16384 + buf * 16384;
    short8 av[4], bv[4];
#pragma unroll
    for (int ni = 0; ni < 4; ++ni)
      bv[ni] = *reinterpret_cast<const short8*>(Bf + bOff + ni * 1024);
#pragma unroll
    for (int mi = 0; mi < 4; ++mi) {
      const f32x4 a0 = *reinterpret_cast<const f32x4*>(Af + aOff0 + mi * 2048);
      const f32x4 a1 = *reinterpret_cast<const f32x4*>(Af + aOff1 + mi * 2048);
      sum4[mi] += ((a0[0] + a0[1]) + (a0[2] + a0[3])) +
                  ((a1[0] + a1[1]) + (a1[2] + a1[3]));
      float q = ssq4[mi];
      q = fmaf(a0[0], a0[0], q); q = fmaf(a0[1], a0[1], q);
      q = fmaf(a0[2], a0[2], q); q = fmaf(a0[3], a0[3], q);
      q = fmaf(a1[0], a1[0], q); q = fmaf(a1[1], a1[1], q);
      q = fmaf(a1[2], a1[2], q); q = fmaf(a1[3], a1[3], q);
      ssq4[mi] = q;
      const u32x4 ua = {pk_bf16(a0[0], a0[1]), pk_bf16(a0[2], a0[3]),
                        pk_bf16(a1[0], a1[1]), pk_bf16(a1[2], a1[3])};
      __builtin_memcpy(&av[mi], &ua, 16);
    }
#pragma unroll
    for (int mi = 0; mi < 4; ++mi)
#pragma unroll
      for (int ni = 0; ni < 4; ++ni)
        acc[mi][ni] = __builtin_amdgcn_mfma_f32_16x16x32_bf16(av[mi], bv[ni],
                                                              acc[mi][ni], 0, 0, 0);
  };

  stage(0, 0);
#pragma unroll 1
  for (int s = 0; s < 32; s += 2) {
    stage(s + 1, 1);
    asm volatile("s_waitcnt vmcnt(6)" ::: "memory");   // group s landed
    __builtin_amdgcn_s_barrier();
    compute(0);
    __builtin_amdgcn_s_barrier();                      // buf0 reads done
    if (s + 2 < 32) {
      stage(s + 2, 0);
      asm volatile("s_waitcnt vmcnt(6)" ::: "memory"); // group s+1 landed
    } else {
      asm volatile("s_waitcnt vmcnt(0)" ::: "memory");
    }
    __builtin_amdgcn_s_barrier();
    compute(1);
    __builtin_amdgcn_s_barrier();                      // buf1 reads done
  }

  // per-wave row stats -> per-wave LDS table
  float* const statsW = stats + w * 128;
#pragma unroll
  for (int mi = 0; mi < 4; ++mi) {
    float s_ = sum4[mi], q_ = ssq4[mi];
    s_ += __shfl_xor(s_, 16); s_ += __shfl_xor(s_, 32);
    q_ += __shfl_xor(q_, 16); q_ += __shfl_xor(q_, 32);
    if (lk == 0) {
      const float mu  = s_ * (1.f / 1024.f);
      const float var = q_ * (1.f / 1024.f) - mu * mu;
      const float rs  = rsqrtf(var + 1e-5f);
      statsW[(mi * 16 + lr) * 2]     = mu * rs;
      statsW[(mi * 16 + lr) * 2 + 1] = rs;
    }
  }
  __syncthreads();

  // epilogue: folded-LN affine -> exact GELU -> second GEMM (256 -> 2)
  float po0[16], po1[16];
#pragma unroll
  for (int i = 0; i < 16; ++i) { po0[i] = 0.f; po1[i] = 0.f; }
#pragma unroll
  for (int ni = 0; ni < 4; ++ni) {
    const int n = w * 64 + ni * 16 + lr;
    const float t2n = t2g[n];
    const float tcn = tc1g[n];
    const float w20 = w2g[n * 2];
    const float w21 = w2g[n * 2 + 1];
#pragma unroll
    for (int mi = 0; mi < 4; ++mi) {
#pragma unroll
      for (int j = 0; j < 4; ++j) {
        const int r = mi * 16 + lk * 4 + j;
        const float mrs = statsW[r * 2];
        const float rs  = statsW[r * 2 + 1];
        const float z  = fmaf(rs, acc[mi][ni][j], fmaf(-mrs, t2n, tcn));
        const float hh = 0.5f * z * (1.f + erff(z * 0.70710678118654752f));
        po0[mi * 4 + j] = fmaf(hh, w20, po0[mi * 4 + j]);
        po1[mi * 4 + j] = fmaf(hh, w21, po1[mi * 4 + j]);
      }
    }
  }
#pragma unroll
  for (int i = 0; i < 16; ++i) {
#pragma unroll
    for (int d = 1; d < 16; d <<= 1) {
      po0[i] += __shfl_xor(po0[i], d);
      po1[i] += __shfl_xor(po1[i], d);
    }
  }
  if (lr == 0) {
#pragma unroll
    for (int mi = 0; mi < 4; ++mi)
#pragma unroll
      for (int j = 0; j < 4; ++j) {
        const int r = mi * 16 + lk * 4 + j;
        pout[(w * 64 + r) * 2 + 0] = po0[mi * 4 + j];
        pout[(w * 64 + r) * 2 + 1] = po1[mi * 4 + j];
      }
  }
  __syncthreads();
  if (t < 128) {
    const int r = t >> 1, o = t & 1;
    const float v = pout[r * 2 + o] + pout[(64 + r) * 2 + o] +
                    pout[(128 + r) * 2 + o] + pout[(192 + r) * 2 + o];
    out[(size_t)(m0 + r) * 2 + o] = v + b2g[o];
  }
}

extern "C" void kernel_launch(void* const* d_in, const int* in_sizes, int n_in,
                              void* d_out, int out_size, void* d_ws, size_t ws_size,
                              hipStream_t stream) {
  const float* emb = (const float*)d_in[0];
  const float* lnw = (const float*)d_in[1];
  const float* lnb = (const float*)d_in[2];
  const float* W1  = (const float*)d_in[3];
  const float* b1  = (const float*)d_in[4];
  const float* W2  = (const float*)d_in[5];
  const float* b2  = (const float*)d_in[6];
  float* out = (float*)d_out;

  unsigned short* w1bt = (unsigned short*)d_ws;                 // 512 KiB
  float* t2g  = (float*)((char*)d_ws + 524288);
  float* tc1g = (float*)((char*)d_ws + 524288 + 1024);

  prep_kernel<<<64, 256, 0, stream>>>(W1, lnw, lnb, b1, w1bt, t2g, tc1g);
  head_kernel<<<65536 / 64, 256, 0, stream>>>(emb, w1bt, t2g, tc1g, W2, b2, out);
}